// Round 12
// baseline (22.075 us; speedup 1.0000x reference)
//
#include <hip/hip_runtime.h>

// B=32, T=4096, D=512, R=64, LOCAL_SIZE=20, SAMPLING_RATE=10, LN_EPS=1e-5
static constexpr int Bsz   = 32;
static constexpr int Tlen  = 4096;
static constexpr int Ddim  = 512;
static constexpr int NSAMP = 408;   // len(range(0, 4076, 10))
static constexpr int NPRES = 20;
static constexpr int NROWS = NSAMP + NPRES;  // 428
static constexpr int RPB   = 64;    // rows per k1 block
static constexpr int NBLK  = 7;     // ceil(428/64)

typedef __attribute__((ext_vector_type(8))) short short8;  // 8 bf16
typedef __attribute__((ext_vector_type(4))) float f32x4;

// HW packed f32->bf16 (RNE). No builtin on gfx950; inline asm per guide T12.
__device__ __forceinline__ unsigned cvt_pk_bf16(float lo, float hi) {
  unsigned r;
  asm("v_cvt_pk_bf16_f32 %0, %1, %2" : "=v"(r) : "v"(lo), "v"(hi));
  return r;
}

// XOR-swizzle for row-major [64][512] bf16 tiles (1024 B rows): breaks the
// 16-rows-same-col bank conflict to 2-way (free). Applied on BOTH LDS
// write and read (reg-staged staging, so legal).
__device__ __forceinline__ int swz(int row, int colByte) {
  return (row << 10) + (colByte ^ ((row & 7) << 4));
}

// K1: cf = LN(ReLU(obs_rows @ w_red + b_red)) for the 428 needed rows.
// Round-11 proven (21.45us): issue-early/write-late staging (T14), both
// MFMA operands in swizzled LDS, 16 waves, no VGPR cap. UNCHANGED.
__global__ __launch_bounds__(1024) void k1_cf(
    const float* __restrict__ obs, const float* __restrict__ wred,
    const float* __restrict__ bred, const float* __restrict__ gred,
    const float* __restrict__ betared,
    float* __restrict__ bpart,     // [B][NBLK][64]
    float* __restrict__ present,   // [B][20][64]
    float* __restrict__ out_now)   // [B][64]
{
  __shared__ short xs[RPB * Ddim];     // 64 KB bf16, swizzled [row][k]
  __shared__ short wt[64 * Ddim];      // 64 KB bf16, swizzled [ch][k]
  __shared__ float sred[64][4];
  __shared__ float s2red[64][4];
  __shared__ float wmax[4][64];

  const int b    = blockIdx.y;
  const int bx   = blockIdx.x;
  const int base = bx * RPB;
  const int tid  = threadIdx.x;
  char* xsB = (char*)xs;
  char* wtB = (char*)wt;

  // ---- STAGE-LOAD: issue all global loads into registers ----
  const float* obs_b = obs + (size_t)b * Tlen * Ddim;
  float4 ov[8];
#pragma unroll
  for (int it = 0; it < 8; ++it) {
    int u    = it * 1024 + tid;       // 0..8191 = 64 rows * 128 float4
    int row  = u >> 7;
    int c4   = u & 127;
    int graw = base + row;
    int gr   = graw < NROWS ? graw : NROWS - 1;   // clamp: benign dup work
    int t    = gr < NSAMP ? gr * 10 : (Tlen - NPRES) + (gr - NSAMP);
    ov[it] = *(const float4*)(obs_b + (size_t)t * Ddim + c4 * 4);
  }
  float4 wva[4], wvb[4];
#pragma unroll
  for (int it = 0; it < 4; ++it) {
    int dp = it * 64 + (tid >> 4);    // k-pair index 0..255
    int d  = dp * 2;
    int r0 = (tid & 15) * 4;
    wva[it] = *(const float4*)(wred + (size_t)d * 64 + r0);
    wvb[it] = *(const float4*)(wred + (size_t)(d + 1) * 64 + r0);
  }

  // ---- STAGE-WRITE: cvt + LDS writes (loads already in flight) ----
#pragma unroll
  for (int it = 0; it < 8; ++it) {
    int u   = it * 1024 + tid;
    int row = u >> 7;
    int c4  = u & 127;
    uint2 wv;
    wv.x = cvt_pk_bf16(ov[it].x, ov[it].y);
    wv.y = cvt_pk_bf16(ov[it].z, ov[it].w);
    *(uint2*)(xsB + swz(row, c4 * 8)) = wv;
  }
#pragma unroll
  for (int it = 0; it < 4; ++it) {
    int dp = it * 64 + (tid >> 4);
    int d  = dp * 2;
    int r0 = (tid & 15) * 4;
    *(unsigned*)(wtB + swz(r0 + 0, d * 2)) = cvt_pk_bf16(wva[it].x, wvb[it].x);
    *(unsigned*)(wtB + swz(r0 + 1, d * 2)) = cvt_pk_bf16(wva[it].y, wvb[it].y);
    *(unsigned*)(wtB + swz(r0 + 2, d * 2)) = cvt_pk_bf16(wva[it].z, wvb[it].z);
    *(unsigned*)(wtB + swz(r0 + 3, d * 2)) = cvt_pk_bf16(wva[it].w, wvb[it].w);
  }
  __syncthreads();

  // ---- MFMA: wave w -> row-group w&3, ch-group w>>2 ----
  const int w    = tid >> 6;
  const int lane = tid & 63;
  const int l15  = lane & 15;
  const int lhi  = lane >> 4;
  const int rowg = w & 3;
  const int chg  = w >> 2;
  const int arow = rowg * 16 + l15;
  const int brow = chg * 16 + l15;

  f32x4 acc = {0.f, 0.f, 0.f, 0.f};
#pragma unroll
  for (int ks = 0; ks < 16; ++ks) {
    int colB = ks * 64 + lhi * 16;    // byte offset of this lane's k-window
    short8 av = *(const short8*)(xsB + swz(arow, colB));
    short8 bv = *(const short8*)(wtB + swz(brow, colB));
    acc = __builtin_amdgcn_mfma_f32_16x16x32_bf16(av, bv, acc, 0, 0, 0);
  }

  // ---- epilogue: bias+ReLU, cross-wave LN ----
  // C/D layout (m89-verified): ch = lane&15, obs row = (lane>>4)*4 + q.
  const int c  = chg * 16 + l15;
  const float bb = bred[c], gg = gred[c], be = betared[c];
  float y[4];
#pragma unroll
  for (int q = 0; q < 4; ++q) {
    y[q] = fmaxf(acc[q] + bb, 0.f);
    float s = y[q], s2 = y[q] * y[q];
#pragma unroll
    for (int msk = 1; msk <= 8; msk <<= 1) {
      s  += __shfl_xor(s,  msk, 64);
      s2 += __shfl_xor(s2, msk, 64);
    }
    if (l15 == 0) {
      int grow = rowg * 16 + lhi * 4 + q;
      sred[grow][chg]  = s;
      s2red[grow][chg] = s2;
    }
  }
  __syncthreads();

  float m = -INFINITY;
  float* pres_b = present + (size_t)b * NPRES * 64;
#pragma unroll
  for (int q = 0; q < 4; ++q) {
    int grow = rowg * 16 + lhi * 4 + q;
    float S  = sred[grow][0] + sred[grow][1] + sred[grow][2] + sred[grow][3];
    float S2 = s2red[grow][0] + s2red[grow][1] + s2red[grow][2] + s2red[grow][3];
    float mean = S * (1.f / 64.f);
    float var  = S2 * (1.f / 64.f) - mean * mean;
    float inv  = rsqrtf(fmaxf(var, 0.f) + 1e-5f);
    float cf   = (y[q] - mean) * inv * gg + be;
    int graw = base + grow;
    int gr   = graw < NROWS ? graw : NROWS - 1;
    if (gr < NSAMP) {
      m = fmaxf(m, cf);
    } else {
      int l = gr - NSAMP;
      pres_b[l * 64 + c] = cf;
      if (gr == NROWS - 1) out_now[b * 64 + c] = cf;
    }
  }

  // block-level sampled max -> bpart (no atomics; deterministic)
  m = fmaxf(m, __shfl_xor(m, 16, 64));
  m = fmaxf(m, __shfl_xor(m, 32, 64));
  if (lhi == 0) wmax[rowg][c] = m;
  __syncthreads();
  if (tid < 64) {
    float mm = fmaxf(fmaxf(wmax[0][tid], wmax[1][tid]),
                     fmaxf(wmax[2][tid], wmax[3][tid]));
    bpart[((size_t)b * NBLK + bx) * 64 + tid] = mm;
  }
}

// K3 v2 (T14): 512 threads, one output-d per thread. The thread's w_exp
// column (64 f32, statically indexed -> registers, rule #20) is issued
// BEFORE the gm prefix-max phase, so its L2 latency hides under it. FMA
// loop is then pure {LDS broadcast + FMA}.
__global__ __launch_bounds__(512) void k3_expand(
    const float* __restrict__ wexp, const float* __restrict__ bexp,
    const float* __restrict__ gexp, const float* __restrict__ betaexp,
    const float* __restrict__ bpart, const float* __restrict__ present,
    float* __restrict__ out_gm)      // [B][20][512]
{
  __shared__ float part[8][64];
  __shared__ float gm[64];
  __shared__ float red_s[8], red_s2[8];
  __shared__ float bc[2];
  const int l = blockIdx.x;   // 0..19
  const int b = blockIdx.y;
  const int tid  = threadIdx.x;      // == output d
  const int lane = tid & 63, wid = tid >> 6;

  // ---- issue w_exp column loads first (independent of gm) ----
  float wreg[64];
#pragma unroll
  for (int i = 0; i < 64; ++i)
    wreg[i] = wexp[(size_t)i * Ddim + tid];
  const float bex = bexp[tid], gex = gexp[tid], bet = betaexp[tid];

  // ---- gm = max(bpart[0..6], present[0..l]), 8-way wave-parallel ----
  const int nsrc = NBLK + l + 1;     // 7 block-partials + l+1 present rows
  float v = -INFINITY;
  for (int s = wid; s < nsrc; s += 8)
    v = fmaxf(v, s < NBLK ? bpart[((size_t)b * NBLK + s) * 64 + lane]
                          : present[((size_t)b * NPRES + (s - NBLK)) * 64 + lane]);
  part[wid][lane] = v;
  __syncthreads();
  if (tid < 64) {
    float m = part[0][tid];
#pragma unroll
    for (int j = 1; j < 8; ++j) m = fmaxf(m, part[j][tid]);
    gm[tid] = m;
  }
  __syncthreads();

  // ---- dot: 64 x {LDS broadcast + FMA} ----
  float a = 0.f;
#pragma unroll
  for (int i = 0; i < 64; ++i)
    a = fmaf(gm[i], wreg[i], a);
  float y = fmaxf(a + bex, 0.f);

  // ---- LN over D=512 ----
  float s = y, s2 = y * y;
#pragma unroll
  for (int m = 32; m >= 1; m >>= 1) {
    s  += __shfl_xor(s,  m, 64);
    s2 += __shfl_xor(s2, m, 64);
  }
  if (lane == 0) { red_s[wid] = s; red_s2[wid] = s2; }
  __syncthreads();
  if (tid == 0) {
    float S = 0.f, S2 = 0.f;
#pragma unroll
    for (int k = 0; k < 8; ++k) { S += red_s[k]; S2 += red_s2[k]; }
    float mean = S * (1.f / 512.f);
    float var  = S2 * (1.f / 512.f) - mean * mean;
    bc[0] = mean;
    bc[1] = rsqrtf(fmaxf(var, 0.f) + 1e-5f);
  }
  __syncthreads();
  out_gm[((size_t)b * NPRES + l) * Ddim + tid] =
      (y - bc[0]) * bc[1] * gex + bet;
}

extern "C" void kernel_launch(void* const* d_in, const int* in_sizes, int n_in,
                              void* d_out, int out_size, void* d_ws, size_t ws_size,
                              hipStream_t stream) {
  const float* obs     = (const float*)d_in[0];
  const float* wred    = (const float*)d_in[1];
  const float* bred    = (const float*)d_in[2];
  const float* gred    = (const float*)d_in[3];
  const float* betared = (const float*)d_in[4];
  const float* wexp    = (const float*)d_in[5];
  const float* bexp    = (const float*)d_in[6];
  const float* gexp    = (const float*)d_in[7];
  const float* betaexp = (const float*)d_in[8];

  float* out_gm  = (float*)d_out;                       // 32*20*512
  float* out_now = (float*)d_out + Bsz * NPRES * Ddim;  // 32*64

  float* bpart   = (float*)d_ws;                        // 32*7*64
  float* present = bpart + Bsz * NBLK * 64;             // 32*20*64

  dim3 g1(NBLK, Bsz);                // 7 x 32 = 224 blocks, 1024 thr
  k1_cf<<<g1, 1024, 0, stream>>>(obs, wred, bred, gred, betared,
                                 bpart, present, out_now);

  dim3 g3(NPRES, Bsz);               // 20 x 32 = 640 blocks, 512 thr
  k3_expand<<<g3, 512, 0, stream>>>(wexp, bexp, gexp, betaexp,
                                    bpart, present, out_gm);
}

// Round 13
// 21.222 us; speedup vs baseline: 1.0402x; 1.0402x over previous
//
#include <hip/hip_runtime.h>

// B=32, T=4096, D=512, R=64, LOCAL_SIZE=20, SAMPLING_RATE=10, LN_EPS=1e-5
static constexpr int Bsz   = 32;
static constexpr int Tlen  = 4096;
static constexpr int Ddim  = 512;
static constexpr int NSAMP = 408;   // len(range(0, 4076, 10))
static constexpr int NPRES = 20;
static constexpr int NROWS = NSAMP + NPRES;  // 428
static constexpr int RPB   = 64;    // rows per k1 block
static constexpr int NBLK  = 7;     // ceil(428/64)

typedef __attribute__((ext_vector_type(8))) short short8;  // 8 bf16
typedef __attribute__((ext_vector_type(4))) float f32x4;

// HW packed f32->bf16 (RNE). No builtin on gfx950; inline asm per guide T12.
__device__ __forceinline__ unsigned cvt_pk_bf16(float lo, float hi) {
  unsigned r;
  asm("v_cvt_pk_bf16_f32 %0, %1, %2" : "=v"(r) : "v"(lo), "v"(hi));
  return r;
}

// XOR-swizzle for row-major [64][512] bf16 tiles (1024 B rows): breaks the
// 16-rows-same-col bank conflict to 2-way (free). Applied on BOTH LDS
// write and read (reg-staged staging, so legal).
__device__ __forceinline__ int swz(int row, int colByte) {
  return (row << 10) + (colByte ^ ((row & 7) << 4));
}

// K1: cf = LN(ReLU(obs_rows @ w_red + b_red)) for the 428 needed rows.
// Round-11 proven (21.45us): issue-early/write-late staging (T14), both
// MFMA operands in swizzled LDS, 16 waves, no VGPR cap.
__global__ __launch_bounds__(1024) void k1_cf(
    const float* __restrict__ obs, const float* __restrict__ wred,
    const float* __restrict__ bred, const float* __restrict__ gred,
    const float* __restrict__ betared,
    float* __restrict__ bpart,     // [B][NBLK][64]
    float* __restrict__ present,   // [B][20][64]
    float* __restrict__ out_now)   // [B][64]
{
  __shared__ short xs[RPB * Ddim];     // 64 KB bf16, swizzled [row][k]
  __shared__ short wt[64 * Ddim];      // 64 KB bf16, swizzled [ch][k]
  __shared__ float sred[64][4];
  __shared__ float s2red[64][4];
  __shared__ float wmax[4][64];

  const int b    = blockIdx.y;
  const int bx   = blockIdx.x;
  const int base = bx * RPB;
  const int tid  = threadIdx.x;
  char* xsB = (char*)xs;
  char* wtB = (char*)wt;

  // ---- STAGE-LOAD: issue all global loads into registers ----
  const float* obs_b = obs + (size_t)b * Tlen * Ddim;
  float4 ov[8];
#pragma unroll
  for (int it = 0; it < 8; ++it) {
    int u    = it * 1024 + tid;       // 0..8191 = 64 rows * 128 float4
    int row  = u >> 7;
    int c4   = u & 127;
    int graw = base + row;
    int gr   = graw < NROWS ? graw : NROWS - 1;   // clamp: benign dup work
    int t    = gr < NSAMP ? gr * 10 : (Tlen - NPRES) + (gr - NSAMP);
    ov[it] = *(const float4*)(obs_b + (size_t)t * Ddim + c4 * 4);
  }
  float4 wva[4], wvb[4];
#pragma unroll
  for (int it = 0; it < 4; ++it) {
    int dp = it * 64 + (tid >> 4);    // k-pair index 0..255
    int d  = dp * 2;
    int r0 = (tid & 15) * 4;
    wva[it] = *(const float4*)(wred + (size_t)d * 64 + r0);
    wvb[it] = *(const float4*)(wred + (size_t)(d + 1) * 64 + r0);
  }

  // ---- STAGE-WRITE: cvt + LDS writes (loads already in flight) ----
#pragma unroll
  for (int it = 0; it < 8; ++it) {
    int u   = it * 1024 + tid;
    int row = u >> 7;
    int c4  = u & 127;
    uint2 wv;
    wv.x = cvt_pk_bf16(ov[it].x, ov[it].y);
    wv.y = cvt_pk_bf16(ov[it].z, ov[it].w);
    *(uint2*)(xsB + swz(row, c4 * 8)) = wv;
  }
#pragma unroll
  for (int it = 0; it < 4; ++it) {
    int dp = it * 64 + (tid >> 4);
    int d  = dp * 2;
    int r0 = (tid & 15) * 4;
    *(unsigned*)(wtB + swz(r0 + 0, d * 2)) = cvt_pk_bf16(wva[it].x, wvb[it].x);
    *(unsigned*)(wtB + swz(r0 + 1, d * 2)) = cvt_pk_bf16(wva[it].y, wvb[it].y);
    *(unsigned*)(wtB + swz(r0 + 2, d * 2)) = cvt_pk_bf16(wva[it].z, wvb[it].z);
    *(unsigned*)(wtB + swz(r0 + 3, d * 2)) = cvt_pk_bf16(wva[it].w, wvb[it].w);
  }
  __syncthreads();

  // ---- MFMA: wave w -> row-group w&3, ch-group w>>2 ----
  const int w    = tid >> 6;
  const int lane = tid & 63;
  const int l15  = lane & 15;
  const int lhi  = lane >> 4;
  const int rowg = w & 3;
  const int chg  = w >> 2;
  const int arow = rowg * 16 + l15;
  const int brow = chg * 16 + l15;

  f32x4 acc = {0.f, 0.f, 0.f, 0.f};
#pragma unroll
  for (int ks = 0; ks < 16; ++ks) {
    int colB = ks * 64 + lhi * 16;    // byte offset of this lane's k-window
    short8 av = *(const short8*)(xsB + swz(arow, colB));
    short8 bv = *(const short8*)(wtB + swz(brow, colB));
    acc = __builtin_amdgcn_mfma_f32_16x16x32_bf16(av, bv, acc, 0, 0, 0);
  }

  // ---- epilogue: bias+ReLU, cross-wave LN ----
  // C/D layout (m89-verified): ch = lane&15, obs row = (lane>>4)*4 + q.
  const int c  = chg * 16 + l15;
  const float bb = bred[c], gg = gred[c], be = betared[c];
  float y[4];
#pragma unroll
  for (int q = 0; q < 4; ++q) {
    y[q] = fmaxf(acc[q] + bb, 0.f);
    float s = y[q], s2 = y[q] * y[q];
#pragma unroll
    for (int msk = 1; msk <= 8; msk <<= 1) {
      s  += __shfl_xor(s,  msk, 64);
      s2 += __shfl_xor(s2, msk, 64);
    }
    if (l15 == 0) {
      int grow = rowg * 16 + lhi * 4 + q;
      sred[grow][chg]  = s;
      s2red[grow][chg] = s2;
    }
  }
  __syncthreads();

  float m = -INFINITY;
  float* pres_b = present + (size_t)b * NPRES * 64;
#pragma unroll
  for (int q = 0; q < 4; ++q) {
    int grow = rowg * 16 + lhi * 4 + q;
    float S  = sred[grow][0] + sred[grow][1] + sred[grow][2] + sred[grow][3];
    float S2 = s2red[grow][0] + s2red[grow][1] + s2red[grow][2] + s2red[grow][3];
    float mean = S * (1.f / 64.f);
    float var  = S2 * (1.f / 64.f) - mean * mean;
    float inv  = rsqrtf(fmaxf(var, 0.f) + 1e-5f);
    float cf   = (y[q] - mean) * inv * gg + be;
    int graw = base + grow;
    int gr   = graw < NROWS ? graw : NROWS - 1;
    if (gr < NSAMP) {
      m = fmaxf(m, cf);
    } else {
      int l = gr - NSAMP;
      pres_b[l * 64 + c] = cf;
      if (gr == NROWS - 1) out_now[b * 64 + c] = cf;
    }
  }

  // block-level sampled max -> bpart (no atomics; deterministic)
  m = fmaxf(m, __shfl_xor(m, 16, 64));
  m = fmaxf(m, __shfl_xor(m, 32, 64));
  if (lhi == 0) wmax[rowg][c] = m;
  __syncthreads();
  if (tid < 64) {
    float mm = fmaxf(fmaxf(wmax[0][tid], wmax[1][tid]),
                     fmaxf(wmax[2][tid], wmax[3][tid]));
    bpart[((size_t)b * NBLK + bx) * 64 + tid] = mm;
  }
}

// K3: one block per (b,l) task, 256 thr (round-11 proven best; the 512-thr
// wreg variant of r12 was neutral-to-negative). 4-wave-parallel prefix
// max, then out = LN(ReLU(gm @ w_exp + b_exp)) over D=512.
__global__ __launch_bounds__(256) void k3_expand(
    const float* __restrict__ wexp, const float* __restrict__ bexp,
    const float* __restrict__ gexp, const float* __restrict__ betaexp,
    const float* __restrict__ bpart, const float* __restrict__ present,
    float* __restrict__ out_gm)      // [B][20][512]
{
  __shared__ float part[4][64];
  __shared__ float gm[64];
  __shared__ float red_s[4], red_s2[4];
  __shared__ float bc[2];
  const int l = blockIdx.x;   // 0..19
  const int b = blockIdx.y;
  const int tid = threadIdx.x;
  const int r = tid & 63, j = tid >> 6;

  const int nsrc = NBLK + l + 1;     // 7 block-partials + l+1 present rows
  float v = -INFINITY;
  for (int s = j; s < nsrc; s += 4)
    v = fmaxf(v, s < NBLK ? bpart[((size_t)b * NBLK + s) * 64 + r]
                          : present[((size_t)b * NPRES + (s - NBLK)) * 64 + r]);
  part[j][r] = v;
  __syncthreads();
  if (tid < 64)
    gm[tid] = fmaxf(fmaxf(part[0][tid], part[1][tid]),
                    fmaxf(part[2][tid], part[3][tid]));
  __syncthreads();

  const int d0 = tid, d1 = tid + 256;
  float a0 = 0.f, a1 = 0.f;
#pragma unroll 8
  for (int rr = 0; rr < 64; ++rr) {
    float g = gm[rr];
    a0 = fmaf(g, wexp[rr * Ddim + d0], a0);
    a1 = fmaf(g, wexp[rr * Ddim + d1], a1);
  }
  float y0 = fmaxf(a0 + bexp[d0], 0.f);
  float y1 = fmaxf(a1 + bexp[d1], 0.f);

  float s = y0 + y1, s2 = fmaf(y0, y0, y1 * y1);
#pragma unroll
  for (int m = 32; m >= 1; m >>= 1) {
    s  += __shfl_xor(s,  m, 64);
    s2 += __shfl_xor(s2, m, 64);
  }
  int wid = tid >> 6, lane = tid & 63;
  if (lane == 0) { red_s[wid] = s; red_s2[wid] = s2; }
  __syncthreads();
  if (tid == 0) {
    float S  = red_s[0] + red_s[1] + red_s[2] + red_s[3];
    float S2 = red_s2[0] + red_s2[1] + red_s2[2] + red_s2[3];
    float mean = S * (1.f / 512.f);
    float var  = S2 * (1.f / 512.f) - mean * mean;
    bc[0] = mean;
    bc[1] = rsqrtf(fmaxf(var, 0.f) + 1e-5f);
  }
  __syncthreads();
  float mean = bc[0], inv = bc[1];
  size_t o = ((size_t)b * NPRES + l) * Ddim;
  out_gm[o + d0] = (y0 - mean) * inv * gexp[d0] + betaexp[d0];
  out_gm[o + d1] = (y1 - mean) * inv * gexp[d1] + betaexp[d1];
}

extern "C" void kernel_launch(void* const* d_in, const int* in_sizes, int n_in,
                              void* d_out, int out_size, void* d_ws, size_t ws_size,
                              hipStream_t stream) {
  const float* obs     = (const float*)d_in[0];
  const float* wred    = (const float*)d_in[1];
  const float* bred    = (const float*)d_in[2];
  const float* gred    = (const float*)d_in[3];
  const float* betared = (const float*)d_in[4];
  const float* wexp    = (const float*)d_in[5];
  const float* bexp    = (const float*)d_in[6];
  const float* gexp    = (const float*)d_in[7];
  const float* betaexp = (const float*)d_in[8];

  float* out_gm  = (float*)d_out;                       // 32*20*512
  float* out_now = (float*)d_out + Bsz * NPRES * Ddim;  // 32*64

  float* bpart   = (float*)d_ws;                        // 32*7*64
  float* present = bpart + Bsz * NBLK * 64;             // 32*20*64

  dim3 g1(NBLK, Bsz);                // 7 x 32 = 224 blocks, 1024 thr
  k1_cf<<<g1, 1024, 0, stream>>>(obs, wred, bred, gred, betared,
                                 bpart, present, out_now);

  dim3 g3(NPRES, Bsz);               // 20 x 32 = 640 blocks
  k3_expand<<<g3, 256, 0, stream>>>(wexp, bexp, gexp, betaexp,
                                    bpart, present, out_gm);
}